// Round 1
// baseline (4510.958 us; speedup 1.0000x reference)
//
#include <hip/hip_runtime.h>

#define NF 64

// ---------- preprocessing ----------
__global__ void k_set1(float* __restrict__ deg, int n) {
    int i = blockIdx.x * 256 + threadIdx.x;
    if (i < n) deg[i] = 1.0f;   // self-loop weight 1
}

__global__ void k_degedge(const int* __restrict__ dst, const float* __restrict__ ew,
                          float* __restrict__ deg, int E) {
    int e = blockIdx.x * 256 + threadIdx.x;
    if (e < E) atomicAdd(&deg[dst[e]], ew[e]);
}

__global__ void k_dinv(float* __restrict__ deg, int n) {
    int i = blockIdx.x * 256 + threadIdx.x;
    if (i < n) {
        float d = deg[i];
        deg[i] = (d > 0.0f) ? rsqrtf(fmaxf(d, 1e-30f)) : 0.0f;
    }
}

__global__ void k_norm(const int* __restrict__ src, const int* __restrict__ dst,
                       const float* __restrict__ ew, const float* __restrict__ dinv,
                       float* __restrict__ nrm, int E, int n) {
    int e = blockIdx.x * 256 + threadIdx.x;
    int tot = E + n;
    if (e >= tot) return;
    int s, d; float w;
    if (e < E) { s = src[e]; d = dst[e]; w = ew[e]; }
    else       { s = d = e - E; w = 1.0f; }
    nrm[e] = dinv[s] * w * dinv[d];
}

// ---------- GEMM: H = act(X) @ W  (X: n x 64, W: 64 x 64) ----------
// 256 threads = 16 rows/block; W column cached in registers, X rows in LDS.
template <int RELU_IN>
__global__ void k_gemm(const float* __restrict__ X, const float* __restrict__ W,
                       float* __restrict__ H, int n) {
    __shared__ float Ws[64 * 64];
    __shared__ float Xs[16][64];
    int tid = threadIdx.x;
#pragma unroll
    for (int i = 0; i < 16; ++i) Ws[tid + i * 256] = W[tid + i * 256];
    int row0 = blockIdx.x * 16;
#pragma unroll
    for (int i = 0; i < 4; ++i) {
        int idx = tid + i * 256;
        int r = idx >> 6, c = idx & 63;
        int gr = row0 + r;
        float v = (gr < n) ? X[gr * NF + c] : 0.0f;
        if (RELU_IN) v = fmaxf(v, 0.0f);
        Xs[r][c] = v;
    }
    __syncthreads();
    int col = tid & 63;
    int rg  = tid >> 6;          // 0..3 -> rows rg*4 .. rg*4+3
    float w[64];
#pragma unroll
    for (int k = 0; k < 64; ++k) w[k] = Ws[k * 64 + col];
    float a0 = 0.f, a1 = 0.f, a2 = 0.f, a3 = 0.f;
#pragma unroll
    for (int k = 0; k < 64; ++k) {
        float wv = w[k];
        a0 += Xs[rg * 4 + 0][k] * wv;
        a1 += Xs[rg * 4 + 1][k] * wv;
        a2 += Xs[rg * 4 + 2][k] * wv;
        a3 += Xs[rg * 4 + 3][k] * wv;
    }
    int gr = row0 + rg * 4;
    if (gr + 3 < n) {
        H[(gr + 0) * NF + col] = a0;
        H[(gr + 1) * NF + col] = a1;
        H[(gr + 2) * NF + col] = a2;
        H[(gr + 3) * NF + col] = a3;
    } else {
        if (gr + 0 < n) H[(gr + 0) * NF + col] = a0;
        if (gr + 1 < n) H[(gr + 1) * NF + col] = a1;
        if (gr + 2 < n) H[(gr + 2) * NF + col] = a2;
        if (gr + 3 < n) H[(gr + 3) * NF + col] = a3;
    }
}

// ---------- init accumulator with bias ----------
__global__ void k_initb(float* __restrict__ agg, const float* __restrict__ b, int n) {
    int i = blockIdx.x * 256 + threadIdx.x;
    if (i < n * NF) agg[i] = b[i & 63];
}

// ---------- edge scatter: agg[dst] += H[src] * norm  (16 lanes/edge, float4) ----------
__global__ void k_scatter(const int* __restrict__ src, const int* __restrict__ dst,
                          const float* __restrict__ nrm, const float* __restrict__ H,
                          float* __restrict__ agg, int E, int n) {
    int idx = blockIdx.x * 256 + threadIdx.x;
    int e = idx >> 4, q = idx & 15;
    int tot = E + n;
    if (e >= tot) return;
    int s, d;
    if (e < E) { s = src[e]; d = dst[e]; }
    else       { s = d = e - E; }
    float nv = nrm[e];
    float4 h = *reinterpret_cast<const float4*>(H + s * NF + q * 4);
    float* ap = agg + d * NF + q * 4;
    atomicAdd(ap + 0, h.x * nv);
    atomicAdd(ap + 1, h.y * nv);
    atomicAdd(ap + 2, h.z * nv);
    atomicAdd(ap + 3, h.w * nv);
}

// ---------- MLP head: y = relu(relu(H) @ Wm1 + bm1) @ Wm2 + bm2, + block min/max ----------
__global__ void k_head(const float* __restrict__ H, const float* __restrict__ Wm1,
                       const float* __restrict__ bm1, const float* __restrict__ Wm2,
                       const float* __restrict__ bm2, float* __restrict__ y,
                       float* __restrict__ pmn, float* __restrict__ pmx, int n) {
    __shared__ float W1s[64 * 16];
    __shared__ float b1s[16];
    __shared__ float W2s[16];
    int tid = threadIdx.x;
    for (int i = tid; i < 64 * 16; i += 256) W1s[i] = Wm1[i];
    if (tid < 16) { b1s[tid] = bm1[tid]; W2s[tid] = Wm2[tid]; }
    __syncthreads();
    int i = blockIdx.x * 256 + tid;
    float yv = 0.0f;
    bool valid = (i < n);
    if (valid) {
        float acc[16];
#pragma unroll
        for (int k = 0; k < 16; ++k) acc[k] = b1s[k];
        const float4* row = reinterpret_cast<const float4*>(H + (size_t)i * NF);
#pragma unroll
        for (int jj = 0; jj < 16; ++jj) {
            float4 v4 = row[jj];
            float hv;
            hv = fmaxf(v4.x, 0.f);
#pragma unroll
            for (int k = 0; k < 16; ++k) acc[k] += hv * W1s[(jj * 4 + 0) * 16 + k];
            hv = fmaxf(v4.y, 0.f);
#pragma unroll
            for (int k = 0; k < 16; ++k) acc[k] += hv * W1s[(jj * 4 + 1) * 16 + k];
            hv = fmaxf(v4.z, 0.f);
#pragma unroll
            for (int k = 0; k < 16; ++k) acc[k] += hv * W1s[(jj * 4 + 2) * 16 + k];
            hv = fmaxf(v4.w, 0.f);
#pragma unroll
            for (int k = 0; k < 16; ++k) acc[k] += hv * W1s[(jj * 4 + 3) * 16 + k];
        }
        yv = bm2[0];
#pragma unroll
        for (int k = 0; k < 16; ++k) yv += fmaxf(acc[k], 0.f) * W2s[k];
        y[i] = yv;
    }
    __shared__ float smn[256], smx[256];
    smn[tid] = valid ? yv : 1e30f;
    smx[tid] = valid ? yv : -1e30f;
    __syncthreads();
    for (int s = 128; s > 0; s >>= 1) {
        if (tid < s) {
            smn[tid] = fminf(smn[tid], smn[tid + s]);
            smx[tid] = fmaxf(smx[tid], smx[tid + s]);
        }
        __syncthreads();
    }
    if (tid == 0) { pmn[blockIdx.x] = smn[0]; pmx[blockIdx.x] = smx[0]; }
}

__global__ void k_minmax(const float* __restrict__ pmn, const float* __restrict__ pmx,
                         float* __restrict__ mm, int nb) {
    __shared__ float smn[512], smx[512];
    int tid = threadIdx.x;
    float mn = 1e30f, mx = -1e30f;
    for (int i = tid; i < nb; i += 512) {
        mn = fminf(mn, pmn[i]);
        mx = fmaxf(mx, pmx[i]);
    }
    smn[tid] = mn; smx[tid] = mx;
    __syncthreads();
    for (int s = 256; s > 0; s >>= 1) {
        if (tid < s) {
            smn[tid] = fminf(smn[tid], smn[tid + s]);
            smx[tid] = fmaxf(smx[tid], smx[tid + s]);
        }
        __syncthreads();
    }
    if (tid == 0) { mm[0] = smn[0]; mm[1] = smx[0]; }
}

__global__ void k_nrm(const float* __restrict__ y, const float* __restrict__ mm,
                      float* __restrict__ out, int n) {
    int i = blockIdx.x * 256 + threadIdx.x;
    if (i >= n) return;
    float mn = mm[0], mx = mm[1];
    out[i] = (y[i] - mn) / (mx - mn);
}

// ---------- launch ----------
extern "C" void kernel_launch(void* const* d_in, const int* in_sizes, int n_in,
                              void* d_out, int out_size, void* d_ws, size_t ws_size,
                              hipStream_t stream) {
    const float* x   = (const float*)d_in[0];
    const int*   ei  = (const int*)d_in[1];
    const float* ep  = (const float*)d_in[2];
    const float* W1  = (const float*)d_in[3];
    const float* b1  = (const float*)d_in[4];
    const float* W2  = (const float*)d_in[5];
    const float* b2  = (const float*)d_in[6];
    const float* W3  = (const float*)d_in[7];
    const float* b3  = (const float*)d_in[8];
    const float* Wm1 = (const float*)d_in[9];
    const float* bm1 = (const float*)d_in[10];
    const float* Wm2 = (const float*)d_in[11];
    const float* bm2 = (const float*)d_in[12];

    const int n = in_sizes[0] / NF;   // 100000
    const int E = in_sizes[2];        // 1600000
    const int* srcv = ei;
    const int* dstv = ei + E;

    float* ws = (float*)d_ws;
    size_t pos = 0;
    auto alloc = [&](size_t cnt) {
        float* p = ws + pos;
        pos += (cnt + 255) & ~(size_t)255;
        return p;
    };
    float* dinv = alloc(n);                  // deg -> dinv in place
    float* nrm  = alloc((size_t)E + n);
    float* y    = alloc(n);
    float* pmn  = alloc(1024);
    float* pmx  = alloc(1024);
    float* mm   = alloc(2);
    float* bufA = alloc((size_t)n * NF);
    float* bufB = alloc((size_t)n * NF);

    const int TPB = 256;
    int gn   = (n + TPB - 1) / TPB;
    int gE   = (E + TPB - 1) / TPB;
    int gEn  = (E + n + TPB - 1) / TPB;
    int gNF  = (n * NF + TPB - 1) / TPB;
    int gG   = (n + 15) / 16;
    int gS   = (int)(((size_t)(E + n) * 16 + TPB - 1) / TPB);
    int gH   = (n + TPB - 1) / TPB;

    // preprocessing (once; reused by all 3 layers)
    k_set1<<<gn, TPB, 0, stream>>>(dinv, n);
    k_degedge<<<gE, TPB, 0, stream>>>(dstv, ep, dinv, E);
    k_dinv<<<gn, TPB, 0, stream>>>(dinv, n);
    k_norm<<<gEn, TPB, 0, stream>>>(srcv, dstv, ep, dinv, nrm, E, n);

    // layer 1: X = x (no relu on read)
    k_gemm<0><<<gG, TPB, 0, stream>>>(x, W1, bufB, n);
    k_initb<<<gNF, TPB, 0, stream>>>(bufA, b1, n);
    k_scatter<<<gS, TPB, 0, stream>>>(srcv, dstv, nrm, bufB, bufA, E, n);

    // layer 2: relu fused into gemm read
    k_gemm<1><<<gG, TPB, 0, stream>>>(bufA, W2, bufB, n);
    k_initb<<<gNF, TPB, 0, stream>>>(bufA, b2, n);
    k_scatter<<<gS, TPB, 0, stream>>>(srcv, dstv, nrm, bufB, bufA, E, n);

    // layer 3
    k_gemm<1><<<gG, TPB, 0, stream>>>(bufA, W3, bufB, n);
    k_initb<<<gNF, TPB, 0, stream>>>(bufA, b3, n);
    k_scatter<<<gS, TPB, 0, stream>>>(srcv, dstv, nrm, bufB, bufA, E, n);

    // head (relu on read) + min/max + normalize
    k_head<<<gH, TPB, 0, stream>>>(bufA, Wm1, bm1, Wm2, bm2, y, pmn, pmx, n);
    k_minmax<<<1, 512, 0, stream>>>(pmn, pmx, mm, gH);
    k_nrm<<<gn, TPB, 0, stream>>>(y, mm, (float*)d_out, n);
}

// Round 2
// 638.207 us; speedup vs baseline: 7.0682x; 7.0682x over previous
//
#include <hip/hip_runtime.h>

#define NF 64

// ================= preprocessing =================
__global__ void k_init(float* __restrict__ deg, int* __restrict__ cnt,
                       int* __restrict__ fill, int n) {
    int i = blockIdx.x * 256 + threadIdx.x;
    if (i < n) { deg[i] = 1.0f; cnt[i] = 1; fill[i] = 0; }  // self-loop
}

__global__ void k_degcnt(const int* __restrict__ dst, const float* __restrict__ ew,
                         float* __restrict__ deg, int* __restrict__ cnt, int E) {
    int e = blockIdx.x * 256 + threadIdx.x;
    if (e < E) {
        int d = dst[e];
        atomicAdd(&deg[d], ew[e]);
        atomicAdd(&cnt[d], 1);
    }
}

__global__ void k_dinv(float* __restrict__ deg, int n) {
    int i = blockIdx.x * 256 + threadIdx.x;
    if (i < n) {
        float d = deg[i];
        deg[i] = (d > 0.0f) ? rsqrtf(fmaxf(d, 1e-30f)) : 0.0f;
    }
}

// ---- exclusive scan of cnt -> rs (1024 elems/block) ----
__global__ void k_scan1(const int* __restrict__ cnt, int* __restrict__ rs,
                        int* __restrict__ btot, int n) {
    __shared__ int s[256];
    int tid = threadIdx.x;
    int base = blockIdx.x * 1024;
    int v[4]; int sum = 0;
#pragma unroll
    for (int j = 0; j < 4; ++j) {
        int idx = base + tid * 4 + j;
        v[j] = (idx < n) ? cnt[idx] : 0;
        sum += v[j];
    }
    s[tid] = sum;
    __syncthreads();
    for (int off = 1; off < 256; off <<= 1) {
        int t = (tid >= off) ? s[tid - off] : 0;
        __syncthreads();
        s[tid] += t;
        __syncthreads();
    }
    int run = s[tid] - sum;   // exclusive prefix within block
#pragma unroll
    for (int j = 0; j < 4; ++j) {
        int idx = base + tid * 4 + j;
        if (idx < n) rs[idx] = run;
        run += v[j];
    }
    if (tid == 255) btot[blockIdx.x] = s[255];
}

__global__ void k_scan2(int* __restrict__ btot, int nb) {
    if (threadIdx.x == 0) {
        int run = 0;
        for (int i = 0; i < nb; ++i) { int t = btot[i]; btot[i] = run; run += t; }
    }
}

__global__ void k_scan3(int* __restrict__ rs, const int* __restrict__ btot,
                        int n, int total) {
    int tid = threadIdx.x;
    int base = blockIdx.x * 1024;
    int off = btot[blockIdx.x];
#pragma unroll
    for (int j = 0; j < 4; ++j) {
        int idx = base + tid * 4 + j;
        if (idx < n) rs[idx] += off;
    }
    if (blockIdx.x == 0 && tid == 0) rs[n] = total;
}

// ---- fill CSR: csr[pos] = {src, norm_weight} ----
__global__ void k_fill(const int* __restrict__ src, const int* __restrict__ dst,
                       const float* __restrict__ ew, const float* __restrict__ dinv,
                       const int* __restrict__ rs, int* __restrict__ fill,
                       int2* __restrict__ csr, int E, int n) {
    int e = blockIdx.x * 256 + threadIdx.x;
    int tot = E + n;
    if (e >= tot) return;
    int s, d; float w;
    if (e < E) { s = src[e]; d = dst[e]; w = ew[e]; }
    else       { s = d = e - E; w = 1.0f; }
    float nv = dinv[s] * w * dinv[d];
    int pos = rs[d] + atomicAdd(&fill[d], 1);
    csr[pos] = make_int2(s, __float_as_int(nv));
}

// ================= GEMM: H = act(X) @ W =================
template <int RELU_IN>
__global__ void k_gemm(const float* __restrict__ X, const float* __restrict__ W,
                       float* __restrict__ H, int n) {
    __shared__ float Ws[64 * 64];
    __shared__ float Xs[16][64];
    int tid = threadIdx.x;
#pragma unroll
    for (int i = 0; i < 16; ++i) Ws[tid + i * 256] = W[tid + i * 256];
    int row0 = blockIdx.x * 16;
#pragma unroll
    for (int i = 0; i < 4; ++i) {
        int idx = tid + i * 256;
        int r = idx >> 6, c = idx & 63;
        int gr = row0 + r;
        float v = (gr < n) ? X[gr * NF + c] : 0.0f;
        if (RELU_IN) v = fmaxf(v, 0.0f);
        Xs[r][c] = v;
    }
    __syncthreads();
    int col = tid & 63;
    int rg  = tid >> 6;
    float w[64];
#pragma unroll
    for (int k = 0; k < 64; ++k) w[k] = Ws[k * 64 + col];
    float a0 = 0.f, a1 = 0.f, a2 = 0.f, a3 = 0.f;
#pragma unroll
    for (int k = 0; k < 64; ++k) {
        float wv = w[k];
        a0 += Xs[rg * 4 + 0][k] * wv;
        a1 += Xs[rg * 4 + 1][k] * wv;
        a2 += Xs[rg * 4 + 2][k] * wv;
        a3 += Xs[rg * 4 + 3][k] * wv;
    }
    int gr = row0 + rg * 4;
    if (gr + 3 < n) {
        H[(gr + 0) * NF + col] = a0;
        H[(gr + 1) * NF + col] = a1;
        H[(gr + 2) * NF + col] = a2;
        H[(gr + 3) * NF + col] = a3;
    } else {
        if (gr + 0 < n) H[(gr + 0) * NF + col] = a0;
        if (gr + 1 < n) H[(gr + 1) * NF + col] = a1;
        if (gr + 2 < n) H[(gr + 2) * NF + col] = a2;
        if (gr + 3 < n) H[(gr + 3) * NF + col] = a3;
    }
}

// ================= CSR gather: out[i] = b + sum_e w_e * H[src_e] =================
// one wave (64 lanes) per node; lane = feature
__global__ void k_gather(const int2* __restrict__ csr, const int* __restrict__ rs,
                         const float* __restrict__ H, const float* __restrict__ b,
                         float* __restrict__ out, int n) {
    int wid  = (blockIdx.x * 256 + threadIdx.x) >> 6;
    int lane = threadIdx.x & 63;
    if (wid >= n) return;
    int beg = rs[wid], end = rs[wid + 1];
    float acc = b[lane];
    int k = beg;
    for (; k + 1 < end; k += 2) {
        int2 p0 = csr[k];
        int2 p1 = csr[k + 1];
        float h0 = H[(size_t)p0.x * NF + lane];
        float h1 = H[(size_t)p1.x * NF + lane];
        acc += __int_as_float(p0.y) * h0;
        acc += __int_as_float(p1.y) * h1;
    }
    if (k < end) {
        int2 p = csr[k];
        acc += __int_as_float(p.y) * H[(size_t)p.x * NF + lane];
    }
    out[(size_t)wid * NF + lane] = acc;
}

// ================= MLP head + min/max =================
__global__ void k_head(const float* __restrict__ H, const float* __restrict__ Wm1,
                       const float* __restrict__ bm1, const float* __restrict__ Wm2,
                       const float* __restrict__ bm2, float* __restrict__ y,
                       float* __restrict__ pmn, float* __restrict__ pmx, int n) {
    __shared__ float W1s[64 * 16];
    __shared__ float b1s[16];
    __shared__ float W2s[16];
    int tid = threadIdx.x;
    for (int i = tid; i < 64 * 16; i += 256) W1s[i] = Wm1[i];
    if (tid < 16) { b1s[tid] = bm1[tid]; W2s[tid] = Wm2[tid]; }
    __syncthreads();
    int i = blockIdx.x * 256 + tid;
    float yv = 0.0f;
    bool valid = (i < n);
    if (valid) {
        float acc[16];
#pragma unroll
        for (int k = 0; k < 16; ++k) acc[k] = b1s[k];
        const float4* row = reinterpret_cast<const float4*>(H + (size_t)i * NF);
#pragma unroll
        for (int jj = 0; jj < 16; ++jj) {
            float4 v4 = row[jj];
            float hv;
            hv = fmaxf(v4.x, 0.f);
#pragma unroll
            for (int k = 0; k < 16; ++k) acc[k] += hv * W1s[(jj * 4 + 0) * 16 + k];
            hv = fmaxf(v4.y, 0.f);
#pragma unroll
            for (int k = 0; k < 16; ++k) acc[k] += hv * W1s[(jj * 4 + 1) * 16 + k];
            hv = fmaxf(v4.z, 0.f);
#pragma unroll
            for (int k = 0; k < 16; ++k) acc[k] += hv * W1s[(jj * 4 + 2) * 16 + k];
            hv = fmaxf(v4.w, 0.f);
#pragma unroll
            for (int k = 0; k < 16; ++k) acc[k] += hv * W1s[(jj * 4 + 3) * 16 + k];
        }
        yv = bm2[0];
#pragma unroll
        for (int k = 0; k < 16; ++k) yv += fmaxf(acc[k], 0.f) * W2s[k];
        y[i] = yv;
    }
    __shared__ float smn[256], smx[256];
    smn[tid] = valid ? yv : 1e30f;
    smx[tid] = valid ? yv : -1e30f;
    __syncthreads();
    for (int s = 128; s > 0; s >>= 1) {
        if (tid < s) {
            smn[tid] = fminf(smn[tid], smn[tid + s]);
            smx[tid] = fmaxf(smx[tid], smx[tid + s]);
        }
        __syncthreads();
    }
    if (tid == 0) { pmn[blockIdx.x] = smn[0]; pmx[blockIdx.x] = smx[0]; }
}

__global__ void k_minmax(const float* __restrict__ pmn, const float* __restrict__ pmx,
                         float* __restrict__ mm, int nb) {
    __shared__ float smn[512], smx[512];
    int tid = threadIdx.x;
    float mn = 1e30f, mx = -1e30f;
    for (int i = tid; i < nb; i += 512) {
        mn = fminf(mn, pmn[i]);
        mx = fmaxf(mx, pmx[i]);
    }
    smn[tid] = mn; smx[tid] = mx;
    __syncthreads();
    for (int s = 256; s > 0; s >>= 1) {
        if (tid < s) {
            smn[tid] = fminf(smn[tid], smn[tid + s]);
            smx[tid] = fmaxf(smx[tid], smx[tid + s]);
        }
        __syncthreads();
    }
    if (tid == 0) { mm[0] = smn[0]; mm[1] = smx[0]; }
}

__global__ void k_nrm(const float* __restrict__ y, const float* __restrict__ mm,
                      float* __restrict__ out, int n) {
    int i = blockIdx.x * 256 + threadIdx.x;
    if (i >= n) return;
    float mn = mm[0], mx = mm[1];
    out[i] = (y[i] - mn) / (mx - mn);
}

// ================= launch =================
extern "C" void kernel_launch(void* const* d_in, const int* in_sizes, int n_in,
                              void* d_out, int out_size, void* d_ws, size_t ws_size,
                              hipStream_t stream) {
    const float* x   = (const float*)d_in[0];
    const int*   ei  = (const int*)d_in[1];
    const float* ep  = (const float*)d_in[2];
    const float* W1  = (const float*)d_in[3];
    const float* b1  = (const float*)d_in[4];
    const float* W2  = (const float*)d_in[5];
    const float* b2  = (const float*)d_in[6];
    const float* W3  = (const float*)d_in[7];
    const float* b3  = (const float*)d_in[8];
    const float* Wm1 = (const float*)d_in[9];
    const float* bm1 = (const float*)d_in[10];
    const float* Wm2 = (const float*)d_in[11];
    const float* bm2 = (const float*)d_in[12];

    const int n = in_sizes[0] / NF;   // 100000
    const int E = in_sizes[2];        // 1600000
    const int* srcv = ei;
    const int* dstv = ei + E;
    const int tot = E + n;

    float* ws = (float*)d_ws;
    size_t pos = 0;
    auto alloc = [&](size_t cnt) {
        float* p = ws + pos;
        pos += (cnt + 255) & ~(size_t)255;
        return p;
    };
    float* dinv = alloc(n);
    int*   cnt  = (int*)alloc(n);
    int*   rs   = (int*)alloc(n + 1);
    int*   fill = (int*)alloc(n);
    int*   btot = (int*)alloc(1024);
    int2*  csr  = (int2*)alloc((size_t)tot * 2);
    float* y    = alloc(n);
    float* pmn  = alloc(1024);
    float* pmx  = alloc(1024);
    float* mm   = alloc(2);
    float* bufA = alloc((size_t)n * NF);
    float* bufB = alloc((size_t)n * NF);

    const int TPB = 256;
    int gn  = (n + TPB - 1) / TPB;
    int gE  = (E + TPB - 1) / TPB;
    int gT  = (tot + TPB - 1) / TPB;
    int gG  = (n + 15) / 16;
    int gW  = (n * 64 + TPB - 1) / TPB;     // gather: 4 nodes/block
    int gH  = (n + TPB - 1) / TPB;
    int nb  = (n + 1023) / 1024;            // scan blocks

    // ---- CSR build (once; reused by all 3 layers) ----
    k_init<<<gn, TPB, 0, stream>>>(dinv, cnt, fill, n);
    k_degcnt<<<gE, TPB, 0, stream>>>(dstv, ep, dinv, cnt, E);
    k_dinv<<<gn, TPB, 0, stream>>>(dinv, n);
    k_scan1<<<nb, TPB, 0, stream>>>(cnt, rs, btot, n);
    k_scan2<<<1, 64, 0, stream>>>(btot, nb);
    k_scan3<<<nb, TPB, 0, stream>>>(rs, btot, n, tot);
    k_fill<<<gT, TPB, 0, stream>>>(srcv, dstv, ep, dinv, rs, fill, csr, E, n);

    // ---- layer 1 ----
    k_gemm<0><<<gG, TPB, 0, stream>>>(x, W1, bufB, n);
    k_gather<<<gW, TPB, 0, stream>>>(csr, rs, bufB, b1, bufA, n);
    // ---- layer 2 ----
    k_gemm<1><<<gG, TPB, 0, stream>>>(bufA, W2, bufB, n);
    k_gather<<<gW, TPB, 0, stream>>>(csr, rs, bufB, b2, bufA, n);
    // ---- layer 3 ----
    k_gemm<1><<<gG, TPB, 0, stream>>>(bufA, W3, bufB, n);
    k_gather<<<gW, TPB, 0, stream>>>(csr, rs, bufB, b3, bufA, n);

    // ---- head + minmax + normalize ----
    k_head<<<gH, TPB, 0, stream>>>(bufA, Wm1, bm1, Wm2, bm2, y, pmn, pmx, n);
    k_minmax<<<1, 512, 0, stream>>>(pmn, pmx, mm, gH);
    k_nrm<<<gn, TPB, 0, stream>>>(y, mm, (float*)d_out, n);
}

// Round 4
// 463.248 us; speedup vs baseline: 9.7377x; 1.3777x over previous
//
#include <hip/hip_runtime.h>

#define NF 64

// ================= CSR build =================
__global__ void k_initcnt(int* __restrict__ cnt, int n) {
    int i = blockIdx.x * 256 + threadIdx.x;
    if (i < n) cnt[i] = 1;              // slot 0 reserved for self-loop
}

// rank[e] = arrival index of edge e within its dst bucket (>=1)
__global__ void k_rank(const int* __restrict__ dst, int* __restrict__ cnt,
                       int* __restrict__ rank, int E) {
    int e = blockIdx.x * 256 + threadIdx.x;
    if (e < E) rank[e] = atomicAdd(&cnt[dst[e]], 1);
}

// ---- exclusive scan of cnt -> rs ----
__global__ void k_scan1(const int* __restrict__ cnt, int* __restrict__ rs,
                        int* __restrict__ btot, int n) {
    __shared__ int s[256];
    int tid = threadIdx.x;
    int base = blockIdx.x * 1024;
    int v[4]; int sum = 0;
#pragma unroll
    for (int j = 0; j < 4; ++j) {
        int idx = base + tid * 4 + j;
        v[j] = (idx < n) ? cnt[idx] : 0;
        sum += v[j];
    }
    s[tid] = sum;
    __syncthreads();
    for (int off = 1; off < 256; off <<= 1) {
        int t = (tid >= off) ? s[tid - off] : 0;
        __syncthreads();
        s[tid] += t;
        __syncthreads();
    }
    int run = s[tid] - sum;
#pragma unroll
    for (int j = 0; j < 4; ++j) {
        int idx = base + tid * 4 + j;
        if (idx < n) rs[idx] = run;
        run += v[j];
    }
    if (tid == 255) btot[blockIdx.x] = s[255];
}

__global__ void k_scan2(int* __restrict__ btot, int nb) {
    if (threadIdx.x == 0) {
        int run = 0;
        for (int i = 0; i < nb; ++i) { int t = btot[i]; btot[i] = run; run += t; }
    }
}

__global__ void k_scan3(int* __restrict__ rs, const int* __restrict__ btot,
                        int n, int total) {
    int tid = threadIdx.x;
    int base = blockIdx.x * 1024;
    int off = btot[blockIdx.x];
#pragma unroll
    for (int j = 0; j < 4; ++j) {
        int idx = base + tid * 4 + j;
        if (idx < n) rs[idx] += off;
    }
    if (blockIdx.x == 0 && tid == 0) rs[n] = total;
}

// ---- fill CSR with RAW weights (no atomics) ----
__global__ void k_fill(const int* __restrict__ src, const int* __restrict__ dst,
                       const float* __restrict__ ew, const int* __restrict__ rs,
                       const int* __restrict__ rank, int2* __restrict__ csr,
                       int E, int n) {
    int e = blockIdx.x * 256 + threadIdx.x;
    int tot = E + n;
    if (e >= tot) return;
    if (e < E) {
        int d = dst[e];
        csr[rs[d] + rank[e]] = make_int2(src[e], __float_as_int(ew[e]));
    } else {
        int i = e - E;
        csr[rs[i]] = make_int2(i, __float_as_int(1.0f));   // self-loop
    }
}

// ---- deg from CSR segments (contiguous, no atomics) -> dinv ----
__global__ void k_deg(const int2* __restrict__ csr, const int* __restrict__ rs,
                      float* __restrict__ dinv, int n) {
    int i = blockIdx.x * 256 + threadIdx.x;
    if (i >= n) return;
    int beg = rs[i], end = rs[i + 1];
    float s = 0.0f;
    for (int k = beg; k < end; ++k) s += __int_as_float(csr[k].y);
    dinv[i] = rsqrtf(fmaxf(s, 1e-30f));
}

// ---- normalize weights in place: w <- dinv[s] * w * dinv[d] ----
__global__ void k_wnorm(int2* __restrict__ csr, const int* __restrict__ rs,
                        const float* __restrict__ dinv, int n) {
    int i = blockIdx.x * 256 + threadIdx.x;
    if (i >= n) return;
    int beg = rs[i], end = rs[i + 1];
    float di = dinv[i];
    for (int k = beg; k < end; ++k) {
        int2 p = csr[k];
        float w = __int_as_float(p.y) * di * dinv[p.x];
        csr[k].y = __float_as_int(w);
    }
}

// ================= GEMM: H = act(X) @ W =================
template <int RELU_IN>
__global__ void k_gemm(const float* __restrict__ X, const float* __restrict__ W,
                       float* __restrict__ H, int n) {
    __shared__ float Ws[64 * 64];
    __shared__ float Xs[16][64];
    int tid = threadIdx.x;
#pragma unroll
    for (int i = 0; i < 16; ++i) Ws[tid + i * 256] = W[tid + i * 256];
    int row0 = blockIdx.x * 16;
#pragma unroll
    for (int i = 0; i < 4; ++i) {
        int idx = tid + i * 256;
        int r = idx >> 6, c = idx & 63;
        int gr = row0 + r;
        float v = (gr < n) ? X[gr * NF + c] : 0.0f;
        if (RELU_IN) v = fmaxf(v, 0.0f);
        Xs[r][c] = v;
    }
    __syncthreads();
    int col = tid & 63;
    int rg  = tid >> 6;
    float w[64];
#pragma unroll
    for (int k = 0; k < 64; ++k) w[k] = Ws[k * 64 + col];
    float a0 = 0.f, a1 = 0.f, a2 = 0.f, a3 = 0.f;
#pragma unroll
    for (int k = 0; k < 64; ++k) {
        float wv = w[k];
        a0 += Xs[rg * 4 + 0][k] * wv;
        a1 += Xs[rg * 4 + 1][k] * wv;
        a2 += Xs[rg * 4 + 2][k] * wv;
        a3 += Xs[rg * 4 + 3][k] * wv;
    }
    int gr = row0 + rg * 4;
    if (gr + 3 < n) {
        H[(gr + 0) * NF + col] = a0;
        H[(gr + 1) * NF + col] = a1;
        H[(gr + 2) * NF + col] = a2;
        H[(gr + 3) * NF + col] = a3;
    } else {
        if (gr + 0 < n) H[(gr + 0) * NF + col] = a0;
        if (gr + 1 < n) H[(gr + 1) * NF + col] = a1;
        if (gr + 2 < n) H[(gr + 2) * NF + col] = a2;
        if (gr + 3 < n) H[(gr + 3) * NF + col] = a3;
    }
}

// ================= CSR gather: out[i] = b + sum_e w_e * H[src_e] =================
// one wave per node; lane = feature; unrolled x4 for MLP
__global__ void k_gather(const int2* __restrict__ csr, const int* __restrict__ rs,
                         const float* __restrict__ H, const float* __restrict__ b,
                         float* __restrict__ out, int n) {
    int wid  = (blockIdx.x * 256 + threadIdx.x) >> 6;
    int lane = threadIdx.x & 63;
    if (wid >= n) return;
    int beg = rs[wid], end = rs[wid + 1];
    float acc = b[lane];
    int k = beg;
    for (; k + 3 < end; k += 4) {
        int2 p0 = csr[k + 0];
        int2 p1 = csr[k + 1];
        int2 p2 = csr[k + 2];
        int2 p3 = csr[k + 3];
        float h0 = H[(size_t)p0.x * NF + lane];
        float h1 = H[(size_t)p1.x * NF + lane];
        float h2 = H[(size_t)p2.x * NF + lane];
        float h3 = H[(size_t)p3.x * NF + lane];
        acc += __int_as_float(p0.y) * h0;
        acc += __int_as_float(p1.y) * h1;
        acc += __int_as_float(p2.y) * h2;
        acc += __int_as_float(p3.y) * h3;
    }
    for (; k < end; ++k) {
        int2 p = csr[k];
        acc += __int_as_float(p.y) * H[(size_t)p.x * NF + lane];
    }
    out[(size_t)wid * NF + lane] = acc;
}

// ================= MLP head + min/max =================
__global__ void k_head(const float* __restrict__ H, const float* __restrict__ Wm1,
                       const float* __restrict__ bm1, const float* __restrict__ Wm2,
                       const float* __restrict__ bm2, float* __restrict__ y,
                       float* __restrict__ pmn, float* __restrict__ pmx, int n) {
    __shared__ float W1s[64 * 16];
    __shared__ float b1s[16];
    __shared__ float W2s[16];
    int tid = threadIdx.x;
    for (int i = tid; i < 64 * 16; i += 256) W1s[i] = Wm1[i];
    if (tid < 16) { b1s[tid] = bm1[tid]; W2s[tid] = Wm2[tid]; }
    __syncthreads();
    int i = blockIdx.x * 256 + tid;
    float yv = 0.0f;
    bool valid = (i < n);
    if (valid) {
        float acc[16];
#pragma unroll
        for (int k = 0; k < 16; ++k) acc[k] = b1s[k];
        const float4* row = reinterpret_cast<const float4*>(H + (size_t)i * NF);
#pragma unroll
        for (int jj = 0; jj < 16; ++jj) {
            float4 v4 = row[jj];
            float hv;
            hv = fmaxf(v4.x, 0.f);
#pragma unroll
            for (int k = 0; k < 16; ++k) acc[k] += hv * W1s[(jj * 4 + 0) * 16 + k];
            hv = fmaxf(v4.y, 0.f);
#pragma unroll
            for (int k = 0; k < 16; ++k) acc[k] += hv * W1s[(jj * 4 + 1) * 16 + k];
            hv = fmaxf(v4.z, 0.f);
#pragma unroll
            for (int k = 0; k < 16; ++k) acc[k] += hv * W1s[(jj * 4 + 2) * 16 + k];
            hv = fmaxf(v4.w, 0.f);
#pragma unroll
            for (int k = 0; k < 16; ++k) acc[k] += hv * W1s[(jj * 4 + 3) * 16 + k];
        }
        yv = bm2[0];
#pragma unroll
        for (int k = 0; k < 16; ++k) yv += fmaxf(acc[k], 0.f) * W2s[k];
        y[i] = yv;
    }
    __shared__ float smn[256], smx[256];
    smn[tid] = valid ? yv : 1e30f;
    smx[tid] = valid ? yv : -1e30f;
    __syncthreads();
    for (int s = 128; s > 0; s >>= 1) {
        if (tid < s) {
            smn[tid] = fminf(smn[tid], smn[tid + s]);
            smx[tid] = fmaxf(smx[tid], smx[tid + s]);
        }
        __syncthreads();
    }
    if (tid == 0) { pmn[blockIdx.x] = smn[0]; pmx[blockIdx.x] = smx[0]; }
}

__global__ void k_minmax(const float* __restrict__ pmn, const float* __restrict__ pmx,
                         float* __restrict__ mm, int nb) {
    __shared__ float smn[512], smx[512];
    int tid = threadIdx.x;
    float mn = 1e30f, mx = -1e30f;
    for (int i = tid; i < nb; i += 512) {
        mn = fminf(mn, pmn[i]);
        mx = fmaxf(mx, pmx[i]);
    }
    smn[tid] = mn; smx[tid] = mx;
    __syncthreads();
    for (int s = 256; s > 0; s >>= 1) {
        if (tid < s) {
            smn[tid] = fminf(smn[tid], smn[tid + s]);
            smx[tid] = fmaxf(smx[tid], smx[tid + s]);
        }
        __syncthreads();
    }
    if (tid == 0) { mm[0] = smn[0]; mm[1] = smx[0]; }
}

__global__ void k_nrm(const float* __restrict__ y, const float* __restrict__ mm,
                      float* __restrict__ out, int n) {
    int i = blockIdx.x * 256 + threadIdx.x;
    if (i >= n) return;
    float mn = mm[0], mx = mm[1];
    out[i] = (y[i] - mn) / (mx - mn);
}

// ================= launch =================
extern "C" void kernel_launch(void* const* d_in, const int* in_sizes, int n_in,
                              void* d_out, int out_size, void* d_ws, size_t ws_size,
                              hipStream_t stream) {
    const float* x   = (const float*)d_in[0];
    const int*   ei  = (const int*)d_in[1];
    const float* ep  = (const float*)d_in[2];
    const float* W1  = (const float*)d_in[3];
    const float* b1  = (const float*)d_in[4];
    const float* W2  = (const float*)d_in[5];
    const float* b2  = (const float*)d_in[6];
    const float* W3  = (const float*)d_in[7];
    const float* b3  = (const float*)d_in[8];
    const float* Wm1 = (const float*)d_in[9];
    const float* bm1 = (const float*)d_in[10];
    const float* Wm2 = (const float*)d_in[11];
    const float* bm2 = (const float*)d_in[12];

    const int n = in_sizes[0] / NF;   // 100000
    const int E = in_sizes[2];        // 1600000
    const int* srcv = ei;
    const int* dstv = ei + E;
    const int tot = E + n;

    float* ws = (float*)d_ws;
    size_t pos = 0;
    auto alloc = [&](size_t cnt) {
        float* p = ws + pos;
        pos += (cnt + 255) & ~(size_t)255;
        return p;
    };
    float* dinv = alloc(n);
    int*   cnt  = (int*)alloc(n);
    int*   rs   = (int*)alloc(n + 1);
    int*   rank = (int*)alloc(E);
    int*   btot = (int*)alloc(1024);
    int2*  csr  = (int2*)alloc((size_t)tot * 2);
    float* y    = alloc(n);
    float* pmn  = alloc(1024);
    float* pmx  = alloc(1024);
    float* mm   = alloc(2);
    float* bufA = alloc((size_t)n * NF);
    float* bufB = alloc((size_t)n * NF);

    const int TPB = 256;
    int gn  = (n + TPB - 1) / TPB;
    int gE  = (E + TPB - 1) / TPB;
    int gT  = (tot + TPB - 1) / TPB;
    int gG  = (n + 15) / 16;
    int gW  = (n * 64 + TPB - 1) / TPB;     // gather: 4 nodes/block
    int gH  = (n + TPB - 1) / TPB;
    int nb  = (n + 1023) / 1024;            // scan blocks

    // ---- CSR build (single atomic pass; reused by all 3 layers) ----
    k_initcnt<<<gn, TPB, 0, stream>>>(cnt, n);
    k_rank<<<gE, TPB, 0, stream>>>(dstv, cnt, rank, E);
    k_scan1<<<nb, TPB, 0, stream>>>(cnt, rs, btot, n);
    k_scan2<<<1, 64, 0, stream>>>(btot, nb);
    k_scan3<<<nb, TPB, 0, stream>>>(rs, btot, n, tot);
    k_fill<<<gT, TPB, 0, stream>>>(srcv, dstv, ep, rs, rank, csr, E, n);
    k_deg<<<gn, TPB, 0, stream>>>(csr, rs, dinv, n);
    k_wnorm<<<gn, TPB, 0, stream>>>(csr, rs, dinv, n);

    // ---- layer 1 ----
    k_gemm<0><<<gG, TPB, 0, stream>>>(x, W1, bufB, n);
    k_gather<<<gW, TPB, 0, stream>>>(csr, rs, bufB, b1, bufA, n);
    // ---- layer 2 ----
    k_gemm<1><<<gG, TPB, 0, stream>>>(bufA, W2, bufB, n);
    k_gather<<<gW, TPB, 0, stream>>>(csr, rs, bufB, b2, bufA, n);
    // ---- layer 3 ----
    k_gemm<1><<<gG, TPB, 0, stream>>>(bufA, W3, bufB, n);
    k_gather<<<gW, TPB, 0, stream>>>(csr, rs, bufB, b3, bufA, n);

    // ---- head + minmax + normalize ----
    k_head<<<gH, TPB, 0, stream>>>(bufA, Wm1, bm1, Wm2, bm2, y, pmn, pmx, n);
    k_minmax<<<1, 512, 0, stream>>>(pmn, pmx, mm, gH);
    k_nrm<<<gn, TPB, 0, stream>>>(y, mm, (float*)d_out, n);
}

// Round 5
// 449.972 us; speedup vs baseline: 10.0250x; 1.0295x over previous
//
#include <hip/hip_runtime.h>

#define NF 64

// bf16 helpers (round-to-nearest-even store, cheap expand load)
__device__ __forceinline__ ushort f2bf(float f) {
    uint u = __float_as_uint(f);
    u += 0x7FFFu + ((u >> 16) & 1u);
    return (ushort)(u >> 16);
}
__device__ __forceinline__ float bf2f(ushort s) {
    return __uint_as_float(((uint)s) << 16);
}

// ================= CSR build =================
__global__ void k_initcnt(int* __restrict__ cnt, int n) {
    int i = blockIdx.x * 256 + threadIdx.x;
    if (i < n) cnt[i] = 1;              // slot 0 reserved for self-loop
}

// rank[e] = arrival index of edge e within its dst bucket (>=1)
__global__ void k_rank(const int* __restrict__ dst, int* __restrict__ cnt,
                       int* __restrict__ rank, int E) {
    int e = blockIdx.x * 256 + threadIdx.x;
    if (e < E) rank[e] = atomicAdd(&cnt[dst[e]], 1);
}

// ---- exclusive scan of cnt -> rs ----
__global__ void k_scan1(const int* __restrict__ cnt, int* __restrict__ rs,
                        int* __restrict__ btot, int n) {
    __shared__ int s[256];
    int tid = threadIdx.x;
    int base = blockIdx.x * 1024;
    int v[4]; int sum = 0;
#pragma unroll
    for (int j = 0; j < 4; ++j) {
        int idx = base + tid * 4 + j;
        v[j] = (idx < n) ? cnt[idx] : 0;
        sum += v[j];
    }
    s[tid] = sum;
    __syncthreads();
    for (int off = 1; off < 256; off <<= 1) {
        int t = (tid >= off) ? s[tid - off] : 0;
        __syncthreads();
        s[tid] += t;
        __syncthreads();
    }
    int run = s[tid] - sum;
#pragma unroll
    for (int j = 0; j < 4; ++j) {
        int idx = base + tid * 4 + j;
        if (idx < n) rs[idx] = run;
        run += v[j];
    }
    if (tid == 255) btot[blockIdx.x] = s[255];
}

__global__ void k_scan2(int* __restrict__ btot, int nb) {
    if (threadIdx.x == 0) {
        int run = 0;
        for (int i = 0; i < nb; ++i) { int t = btot[i]; btot[i] = run; run += t; }
    }
}

__global__ void k_scan3(int* __restrict__ rs, const int* __restrict__ btot,
                        int n, int total) {
    int tid = threadIdx.x;
    int base = blockIdx.x * 1024;
    int off = btot[blockIdx.x];
#pragma unroll
    for (int j = 0; j < 4; ++j) {
        int idx = base + tid * 4 + j;
        if (idx < n) rs[idx] += off;
    }
    if (blockIdx.x == 0 && tid == 0) rs[n] = total;
}

// ---- fill CSR with RAW weights (no atomics) ----
__global__ void k_fill(const int* __restrict__ src, const int* __restrict__ dst,
                       const float* __restrict__ ew, const int* __restrict__ rs,
                       const int* __restrict__ rank, int2* __restrict__ csr,
                       int E, int n) {
    int e = blockIdx.x * 256 + threadIdx.x;
    int tot = E + n;
    if (e >= tot) return;
    if (e < E) {
        int d = dst[e];
        csr[rs[d] + rank[e]] = make_int2(src[e], __float_as_int(ew[e]));
    } else {
        int i = e - E;
        csr[rs[i]] = make_int2(i, __float_as_int(1.0f));   // self-loop
    }
}

// ---- deg from CSR segments (contiguous, no atomics) -> dinv ----
__global__ void k_deg(const int2* __restrict__ csr, const int* __restrict__ rs,
                      float* __restrict__ dinv, int n) {
    int i = blockIdx.x * 256 + threadIdx.x;
    if (i >= n) return;
    int beg = rs[i], end = rs[i + 1];
    float s = 0.0f;
    for (int k = beg; k < end; ++k) s += __int_as_float(csr[k].y);
    dinv[i] = rsqrtf(fmaxf(s, 1e-30f));
}

// ---- normalize weights in place: w <- dinv[s] * w * dinv[d] ----
__global__ void k_wnorm(int2* __restrict__ csr, const int* __restrict__ rs,
                        const float* __restrict__ dinv, int n) {
    int i = blockIdx.x * 256 + threadIdx.x;
    if (i >= n) return;
    int beg = rs[i], end = rs[i + 1];
    float di = dinv[i];
    for (int k = beg; k < end; ++k) {
        int2 p = csr[k];
        float w = __int_as_float(p.y) * di * dinv[p.x];
        csr[k].y = __float_as_int(w);
    }
}

// ================= GEMM: H = act(X) @ W, H stored bf16 =================
template <int RELU_IN>
__global__ void k_gemm(const float* __restrict__ X, const float* __restrict__ W,
                       ushort* __restrict__ H, int n) {
    __shared__ float Ws[64 * 64];
    __shared__ float Xs[16][64];
    int tid = threadIdx.x;
#pragma unroll
    for (int i = 0; i < 16; ++i) Ws[tid + i * 256] = W[tid + i * 256];
    int row0 = blockIdx.x * 16;
#pragma unroll
    for (int i = 0; i < 4; ++i) {
        int idx = tid + i * 256;
        int r = idx >> 6, c = idx & 63;
        int gr = row0 + r;
        float v = (gr < n) ? X[gr * NF + c] : 0.0f;
        if (RELU_IN) v = fmaxf(v, 0.0f);
        Xs[r][c] = v;
    }
    __syncthreads();
    int col = tid & 63;
    int rg  = tid >> 6;
    float w[64];
#pragma unroll
    for (int k = 0; k < 64; ++k) w[k] = Ws[k * 64 + col];
    float a0 = 0.f, a1 = 0.f, a2 = 0.f, a3 = 0.f;
#pragma unroll
    for (int k = 0; k < 64; ++k) {
        float wv = w[k];
        a0 += Xs[rg * 4 + 0][k] * wv;
        a1 += Xs[rg * 4 + 1][k] * wv;
        a2 += Xs[rg * 4 + 2][k] * wv;
        a3 += Xs[rg * 4 + 3][k] * wv;
    }
    int gr = row0 + rg * 4;
    if (gr + 3 < n) {
        H[(gr + 0) * NF + col] = f2bf(a0);
        H[(gr + 1) * NF + col] = f2bf(a1);
        H[(gr + 2) * NF + col] = f2bf(a2);
        H[(gr + 3) * NF + col] = f2bf(a3);
    } else {
        if (gr + 0 < n) H[(gr + 0) * NF + col] = f2bf(a0);
        if (gr + 1 < n) H[(gr + 1) * NF + col] = f2bf(a1);
        if (gr + 2 < n) H[(gr + 2) * NF + col] = f2bf(a2);
        if (gr + 3 < n) H[(gr + 3) * NF + col] = f2bf(a3);
    }
}

// ================= CSR gather: out[i] = b + sum_e w_e * H[src_e] =================
// one wave per node; lane = feature; H rows bf16 (128 B), fp32 accumulate
__global__ void k_gather(const int2* __restrict__ csr, const int* __restrict__ rs,
                         const ushort* __restrict__ H, const float* __restrict__ b,
                         float* __restrict__ out, int n) {
    int wid  = (blockIdx.x * 256 + threadIdx.x) >> 6;
    int lane = threadIdx.x & 63;
    if (wid >= n) return;
    int beg = rs[wid], end = rs[wid + 1];
    float acc = b[lane];
    int k = beg;
    for (; k + 3 < end; k += 4) {
        int2 p0 = csr[k + 0];
        int2 p1 = csr[k + 1];
        int2 p2 = csr[k + 2];
        int2 p3 = csr[k + 3];
        float h0 = bf2f(H[(size_t)p0.x * NF + lane]);
        float h1 = bf2f(H[(size_t)p1.x * NF + lane]);
        float h2 = bf2f(H[(size_t)p2.x * NF + lane]);
        float h3 = bf2f(H[(size_t)p3.x * NF + lane]);
        acc += __int_as_float(p0.y) * h0;
        acc += __int_as_float(p1.y) * h1;
        acc += __int_as_float(p2.y) * h2;
        acc += __int_as_float(p3.y) * h3;
    }
    for (; k < end; ++k) {
        int2 p = csr[k];
        acc += __int_as_float(p.y) * bf2f(H[(size_t)p.x * NF + lane]);
    }
    out[(size_t)wid * NF + lane] = acc;
}

// ================= MLP head + min/max =================
__global__ void k_head(const float* __restrict__ H, const float* __restrict__ Wm1,
                       const float* __restrict__ bm1, const float* __restrict__ Wm2,
                       const float* __restrict__ bm2, float* __restrict__ y,
                       float* __restrict__ pmn, float* __restrict__ pmx, int n) {
    __shared__ float W1s[64 * 16];
    __shared__ float b1s[16];
    __shared__ float W2s[16];
    int tid = threadIdx.x;
    for (int i = tid; i < 64 * 16; i += 256) W1s[i] = Wm1[i];
    if (tid < 16) { b1s[tid] = bm1[tid]; W2s[tid] = Wm2[tid]; }
    __syncthreads();
    int i = blockIdx.x * 256 + tid;
    float yv = 0.0f;
    bool valid = (i < n);
    if (valid) {
        float acc[16];
#pragma unroll
        for (int k = 0; k < 16; ++k) acc[k] = b1s[k];
        const float4* row = reinterpret_cast<const float4*>(H + (size_t)i * NF);
#pragma unroll
        for (int jj = 0; jj < 16; ++jj) {
            float4 v4 = row[jj];
            float hv;
            hv = fmaxf(v4.x, 0.f);
#pragma unroll
            for (int k = 0; k < 16; ++k) acc[k] += hv * W1s[(jj * 4 + 0) * 16 + k];
            hv = fmaxf(v4.y, 0.f);
#pragma unroll
            for (int k = 0; k < 16; ++k) acc[k] += hv * W1s[(jj * 4 + 1) * 16 + k];
            hv = fmaxf(v4.z, 0.f);
#pragma unroll
            for (int k = 0; k < 16; ++k) acc[k] += hv * W1s[(jj * 4 + 2) * 16 + k];
            hv = fmaxf(v4.w, 0.f);
#pragma unroll
            for (int k = 0; k < 16; ++k) acc[k] += hv * W1s[(jj * 4 + 3) * 16 + k];
        }
        yv = bm2[0];
#pragma unroll
        for (int k = 0; k < 16; ++k) yv += fmaxf(acc[k], 0.f) * W2s[k];
        y[i] = yv;
    }
    __shared__ float smn[256], smx[256];
    smn[tid] = valid ? yv : 1e30f;
    smx[tid] = valid ? yv : -1e30f;
    __syncthreads();
    for (int s = 128; s > 0; s >>= 1) {
        if (tid < s) {
            smn[tid] = fminf(smn[tid], smn[tid + s]);
            smx[tid] = fmaxf(smx[tid], smx[tid + s]);
        }
        __syncthreads();
    }
    if (tid == 0) { pmn[blockIdx.x] = smn[0]; pmx[blockIdx.x] = smx[0]; }
}

__global__ void k_minmax(const float* __restrict__ pmn, const float* __restrict__ pmx,
                         float* __restrict__ mm, int nb) {
    __shared__ float smn[512], smx[512];
    int tid = threadIdx.x;
    float mn = 1e30f, mx = -1e30f;
    for (int i = tid; i < nb; i += 512) {
        mn = fminf(mn, pmn[i]);
        mx = fmaxf(mx, pmx[i]);
    }
    smn[tid] = mn; smx[tid] = mx;
    __syncthreads();
    for (int s = 256; s > 0; s >>= 1) {
        if (tid < s) {
            smn[tid] = fminf(smn[tid], smn[tid + s]);
            smx[tid] = fmaxf(smx[tid], smx[tid + s]);
        }
        __syncthreads();
    }
    if (tid == 0) { mm[0] = smn[0]; mm[1] = smx[0]; }
}

__global__ void k_nrm(const float* __restrict__ y, const float* __restrict__ mm,
                      float* __restrict__ out, int n) {
    int i = blockIdx.x * 256 + threadIdx.x;
    if (i >= n) return;
    float mn = mm[0], mx = mm[1];
    out[i] = (y[i] - mn) / (mx - mn);
}

// ================= launch =================
extern "C" void kernel_launch(void* const* d_in, const int* in_sizes, int n_in,
                              void* d_out, int out_size, void* d_ws, size_t ws_size,
                              hipStream_t stream) {
    const float* x   = (const float*)d_in[0];
    const int*   ei  = (const int*)d_in[1];
    const float* ep  = (const float*)d_in[2];
    const float* W1  = (const float*)d_in[3];
    const float* b1  = (const float*)d_in[4];
    const float* W2  = (const float*)d_in[5];
    const float* b2  = (const float*)d_in[6];
    const float* W3  = (const float*)d_in[7];
    const float* b3  = (const float*)d_in[8];
    const float* Wm1 = (const float*)d_in[9];
    const float* bm1 = (const float*)d_in[10];
    const float* Wm2 = (const float*)d_in[11];
    const float* bm2 = (const float*)d_in[12];

    const int n = in_sizes[0] / NF;   // 100000
    const int E = in_sizes[2];        // 1600000
    const int* srcv = ei;
    const int* dstv = ei + E;
    const int tot = E + n;

    float* ws = (float*)d_ws;
    size_t pos = 0;
    auto alloc = [&](size_t cnt) {
        float* p = ws + pos;
        pos += (cnt + 255) & ~(size_t)255;
        return p;
    };
    float*  dinv = alloc(n);
    int*    cnt  = (int*)alloc(n);
    int*    rs   = (int*)alloc(n + 1);
    int*    rank = (int*)alloc(E);
    int*    btot = (int*)alloc(1024);
    int2*   csr  = (int2*)alloc((size_t)tot * 2);
    float*  y    = alloc(n);
    float*  pmn  = alloc(1024);
    float*  pmx  = alloc(1024);
    float*  mm   = alloc(2);
    float*  bufA = alloc((size_t)n * NF);            // fp32 agg
    ushort* bufH = (ushort*)alloc((size_t)n * NF / 2); // bf16 H

    const int TPB = 256;
    int gn  = (n + TPB - 1) / TPB;
    int gE  = (E + TPB - 1) / TPB;
    int gT  = (tot + TPB - 1) / TPB;
    int gG  = (n + 15) / 16;
    int gW  = (n * 64 + TPB - 1) / TPB;     // gather: 4 nodes/block
    int gH  = (n + TPB - 1) / TPB;
    int nb  = (n + 1023) / 1024;            // scan blocks

    // ---- CSR build (single atomic pass; reused by all 3 layers) ----
    k_initcnt<<<gn, TPB, 0, stream>>>(cnt, n);
    k_rank<<<gE, TPB, 0, stream>>>(dstv, cnt, rank, E);
    k_scan1<<<nb, TPB, 0, stream>>>(cnt, rs, btot, n);
    k_scan2<<<1, 64, 0, stream>>>(btot, nb);
    k_scan3<<<nb, TPB, 0, stream>>>(rs, btot, n, tot);
    k_fill<<<gT, TPB, 0, stream>>>(srcv, dstv, ep, rs, rank, csr, E, n);
    k_deg<<<gn, TPB, 0, stream>>>(csr, rs, dinv, n);
    k_wnorm<<<gn, TPB, 0, stream>>>(csr, rs, dinv, n);

    // ---- layer 1 ----
    k_gemm<0><<<gG, TPB, 0, stream>>>(x, W1, bufH, n);
    k_gather<<<gW, TPB, 0, stream>>>(csr, rs, bufH, b1, bufA, n);
    // ---- layer 2 ----
    k_gemm<1><<<gG, TPB, 0, stream>>>(bufA, W2, bufH, n);
    k_gather<<<gW, TPB, 0, stream>>>(csr, rs, bufH, b2, bufA, n);
    // ---- layer 3 ----
    k_gemm<1><<<gG, TPB, 0, stream>>>(bufA, W3, bufH, n);
    k_gather<<<gW, TPB, 0, stream>>>(csr, rs, bufH, b3, bufA, n);

    // ---- head + minmax + normalize ----
    k_head<<<gH, TPB, 0, stream>>>(bufA, Wm1, bm1, Wm2, bm2, y, pmn, pmx, n);
    k_minmax<<<1, 512, 0, stream>>>(pmn, pmx, mm, gH);
    k_nrm<<<gn, TPB, 0, stream>>>(y, mm, (float*)d_out, n);
}

// Round 6
// 412.619 us; speedup vs baseline: 10.9325x; 1.0905x over previous
//
#include <hip/hip_runtime.h>

#define NF 64

// bf16 helpers (round-to-nearest-even store, cheap expand load)
__device__ __forceinline__ ushort f2bf(float f) {
    uint u = __float_as_uint(f);
    u += 0x7FFFu + ((u >> 16) & 1u);
    return (ushort)(u >> 16);
}

// ================= CSR build =================
__global__ void k_initcnt(int* __restrict__ cnt, int n) {
    int i = blockIdx.x * 256 + threadIdx.x;
    if (i < n) cnt[i] = 1;              // slot 0 reserved for self-loop
}

// rank[e] = arrival index of edge e within its dst bucket (>=1)
__global__ void k_rank(const int* __restrict__ dst, int* __restrict__ cnt,
                       int* __restrict__ rank, int E) {
    int e = blockIdx.x * 256 + threadIdx.x;
    if (e < E) rank[e] = atomicAdd(&cnt[dst[e]], 1);
}

// ---- exclusive scan of cnt -> rs ----
__global__ void k_scan1(const int* __restrict__ cnt, int* __restrict__ rs,
                        int* __restrict__ btot, int n) {
    __shared__ int s[256];
    int tid = threadIdx.x;
    int base = blockIdx.x * 1024;
    int v[4]; int sum = 0;
#pragma unroll
    for (int j = 0; j < 4; ++j) {
        int idx = base + tid * 4 + j;
        v[j] = (idx < n) ? cnt[idx] : 0;
        sum += v[j];
    }
    s[tid] = sum;
    __syncthreads();
    for (int off = 1; off < 256; off <<= 1) {
        int t = (tid >= off) ? s[tid - off] : 0;
        __syncthreads();
        s[tid] += t;
        __syncthreads();
    }
    int run = s[tid] - sum;
#pragma unroll
    for (int j = 0; j < 4; ++j) {
        int idx = base + tid * 4 + j;
        if (idx < n) rs[idx] = run;
        run += v[j];
    }
    if (tid == 255) btot[blockIdx.x] = s[255];
}

__global__ void k_scan2(int* __restrict__ btot, int nb) {
    if (threadIdx.x == 0) {
        int run = 0;
        for (int i = 0; i < nb; ++i) { int t = btot[i]; btot[i] = run; run += t; }
    }
}

__global__ void k_scan3(int* __restrict__ rs, const int* __restrict__ btot,
                        int n, int total) {
    int tid = threadIdx.x;
    int base = blockIdx.x * 1024;
    int off = btot[blockIdx.x];
#pragma unroll
    for (int j = 0; j < 4; ++j) {
        int idx = base + tid * 4 + j;
        if (idx < n) rs[idx] += off;
    }
    if (blockIdx.x == 0 && tid == 0) rs[n] = total;
}

// ---- fill CSR with RAW weights (no atomics) ----
__global__ void k_fill(const int* __restrict__ src, const int* __restrict__ dst,
                       const float* __restrict__ ew, const int* __restrict__ rs,
                       const int* __restrict__ rank, int2* __restrict__ csr,
                       int E, int n) {
    int e = blockIdx.x * 256 + threadIdx.x;
    int tot = E + n;
    if (e >= tot) return;
    if (e < E) {
        int d = dst[e];
        csr[rs[d] + rank[e]] = make_int2(src[e], __float_as_int(ew[e]));
    } else {
        int i = e - E;
        csr[rs[i]] = make_int2(i, __float_as_int(1.0f));   // self-loop
    }
}

// ---- deg from CSR segments (contiguous, no atomics) -> dinv ----
__global__ void k_deg(const int2* __restrict__ csr, const int* __restrict__ rs,
                      float* __restrict__ dinv, int n) {
    int i = blockIdx.x * 256 + threadIdx.x;
    if (i >= n) return;
    int beg = rs[i], end = rs[i + 1];
    float s = 0.0f;
    for (int k = beg; k < end; ++k) s += __int_as_float(csr[k].y);
    dinv[i] = rsqrtf(fmaxf(s, 1e-30f));
}

// ---- normalize weights in place: w <- dinv[s] * w * dinv[d] ----
__global__ void k_wnorm(int2* __restrict__ csr, const int* __restrict__ rs,
                        const float* __restrict__ dinv, int n) {
    int i = blockIdx.x * 256 + threadIdx.x;
    if (i >= n) return;
    int beg = rs[i], end = rs[i + 1];
    float di = dinv[i];
    for (int k = beg; k < end; ++k) {
        int2 p = csr[k];
        float w = __int_as_float(p.y) * di * dinv[p.x];
        csr[k].y = __float_as_int(w);
    }
}

// ================= GEMM: H = act(X) @ W, H stored bf16 =================
template <int RELU_IN>
__global__ void k_gemm(const float* __restrict__ X, const float* __restrict__ W,
                       ushort* __restrict__ H, int n) {
    __shared__ float Ws[64 * 64];
    __shared__ float Xs[16][64];
    int tid = threadIdx.x;
#pragma unroll
    for (int i = 0; i < 16; ++i) Ws[tid + i * 256] = W[tid + i * 256];
    int row0 = blockIdx.x * 16;
#pragma unroll
    for (int i = 0; i < 4; ++i) {
        int idx = tid + i * 256;
        int r = idx >> 6, c = idx & 63;
        int gr = row0 + r;
        float v = (gr < n) ? X[gr * NF + c] : 0.0f;
        if (RELU_IN) v = fmaxf(v, 0.0f);
        Xs[r][c] = v;
    }
    __syncthreads();
    int col = tid & 63;
    int rg  = tid >> 6;
    float w[64];
#pragma unroll
    for (int k = 0; k < 64; ++k) w[k] = Ws[k * 64 + col];
    float a0 = 0.f, a1 = 0.f, a2 = 0.f, a3 = 0.f;
#pragma unroll
    for (int k = 0; k < 64; ++k) {
        float wv = w[k];
        a0 += Xs[rg * 4 + 0][k] * wv;
        a1 += Xs[rg * 4 + 1][k] * wv;
        a2 += Xs[rg * 4 + 2][k] * wv;
        a3 += Xs[rg * 4 + 3][k] * wv;
    }
    int gr = row0 + rg * 4;
    if (gr + 3 < n) {
        H[(gr + 0) * NF + col] = f2bf(a0);
        H[(gr + 1) * NF + col] = f2bf(a1);
        H[(gr + 2) * NF + col] = f2bf(a2);
        H[(gr + 3) * NF + col] = f2bf(a3);
    } else {
        if (gr + 0 < n) H[(gr + 0) * NF + col] = f2bf(a0);
        if (gr + 1 < n) H[(gr + 1) * NF + col] = f2bf(a1);
        if (gr + 2 < n) H[(gr + 2) * NF + col] = f2bf(a2);
        if (gr + 3 < n) H[(gr + 3) * NF + col] = f2bf(a3);
    }
}

// ================= CSR gather: out[i] = b + sum_e w_e * H[src_e] =================
// wave = node. 2 groups x 32 lanes; group g handles edges beg+g, beg+g+2, ...
// lane loads uint (2 bf16) -> 1 load instruction per edge-row, 2 independent
// chains, unroll 4 per group = 8 rows in flight per wave.
__global__ void k_gather(const int2* __restrict__ csr, const int* __restrict__ rs,
                         const ushort* __restrict__ H, const float* __restrict__ b,
                         float* __restrict__ out, int n) {
    int wid  = (blockIdx.x * 256 + threadIdx.x) >> 6;
    int lane = threadIdx.x & 63;
    if (wid >= n) return;
    int g   = lane >> 5;          // edge group 0/1
    int sub = lane & 31;          // feature-pair index (features 2*sub, 2*sub+1)
    int beg = rs[wid], end = rs[wid + 1];
    float ax = 0.f, ay = 0.f;
    int k = beg + g;
    for (; k + 6 < end; k += 8) {
        int2 p0 = csr[k + 0];
        int2 p1 = csr[k + 2];
        int2 p2 = csr[k + 4];
        int2 p3 = csr[k + 6];
        uint h0 = *reinterpret_cast<const uint*>(H + (size_t)p0.x * NF + sub * 2);
        uint h1 = *reinterpret_cast<const uint*>(H + (size_t)p1.x * NF + sub * 2);
        uint h2 = *reinterpret_cast<const uint*>(H + (size_t)p2.x * NF + sub * 2);
        uint h3 = *reinterpret_cast<const uint*>(H + (size_t)p3.x * NF + sub * 2);
        float w0 = __int_as_float(p0.y);
        float w1 = __int_as_float(p1.y);
        float w2 = __int_as_float(p2.y);
        float w3 = __int_as_float(p3.y);
        ax += w0 * __uint_as_float(h0 << 16);
        ay += w0 * __uint_as_float(h0 & 0xFFFF0000u);
        ax += w1 * __uint_as_float(h1 << 16);
        ay += w1 * __uint_as_float(h1 & 0xFFFF0000u);
        ax += w2 * __uint_as_float(h2 << 16);
        ay += w2 * __uint_as_float(h2 & 0xFFFF0000u);
        ax += w3 * __uint_as_float(h3 << 16);
        ay += w3 * __uint_as_float(h3 & 0xFFFF0000u);
    }
    for (; k < end; k += 2) {
        int2 p = csr[k];
        uint h = *reinterpret_cast<const uint*>(H + (size_t)p.x * NF + sub * 2);
        float w = __int_as_float(p.y);
        ax += w * __uint_as_float(h << 16);
        ay += w * __uint_as_float(h & 0xFFFF0000u);
    }
    // combine the two edge groups
    ax += __shfl_xor(ax, 32);
    ay += __shfl_xor(ay, 32);
    if (g == 0) {
        const float2* bp = reinterpret_cast<const float2*>(b);
        float2 bb = bp[sub];
        float2 o = make_float2(ax + bb.x, ay + bb.y);
        *reinterpret_cast<float2*>(out + (size_t)wid * NF + sub * 2) = o;
    }
}

// ================= MLP head + min/max =================
__global__ void k_head(const float* __restrict__ H, const float* __restrict__ Wm1,
                       const float* __restrict__ bm1, const float* __restrict__ Wm2,
                       const float* __restrict__ bm2, float* __restrict__ y,
                       float* __restrict__ pmn, float* __restrict__ pmx, int n) {
    __shared__ float W1s[64 * 16];
    __shared__ float b1s[16];
    __shared__ float W2s[16];
    int tid = threadIdx.x;
    for (int i = tid; i < 64 * 16; i += 256) W1s[i] = Wm1[i];
    if (tid < 16) { b1s[tid] = bm1[tid]; W2s[tid] = Wm2[tid]; }
    __syncthreads();
    int i = blockIdx.x * 256 + tid;
    float yv = 0.0f;
    bool valid = (i < n);
    if (valid) {
        float acc[16];
#pragma unroll
        for (int k = 0; k < 16; ++k) acc[k] = b1s[k];
        const float4* row = reinterpret_cast<const float4*>(H + (size_t)i * NF);
#pragma unroll
        for (int jj = 0; jj < 16; ++jj) {
            float4 v4 = row[jj];
            float hv;
            hv = fmaxf(v4.x, 0.f);
#pragma unroll
            for (int k = 0; k < 16; ++k) acc[k] += hv * W1s[(jj * 4 + 0) * 16 + k];
            hv = fmaxf(v4.y, 0.f);
#pragma unroll
            for (int k = 0; k < 16; ++k) acc[k] += hv * W1s[(jj * 4 + 1) * 16 + k];
            hv = fmaxf(v4.z, 0.f);
#pragma unroll
            for (int k = 0; k < 16; ++k) acc[k] += hv * W1s[(jj * 4 + 2) * 16 + k];
            hv = fmaxf(v4.w, 0.f);
#pragma unroll
            for (int k = 0; k < 16; ++k) acc[k] += hv * W1s[(jj * 4 + 3) * 16 + k];
        }
        yv = bm2[0];
#pragma unroll
        for (int k = 0; k < 16; ++k) yv += fmaxf(acc[k], 0.f) * W2s[k];
        y[i] = yv;
    }
    __shared__ float smn[256], smx[256];
    smn[tid] = valid ? yv : 1e30f;
    smx[tid] = valid ? yv : -1e30f;
    __syncthreads();
    for (int s = 128; s > 0; s >>= 1) {
        if (tid < s) {
            smn[tid] = fminf(smn[tid], smn[tid + s]);
            smx[tid] = fmaxf(smx[tid], smx[tid + s]);
        }
        __syncthreads();
    }
    if (tid == 0) { pmn[blockIdx.x] = smn[0]; pmx[blockIdx.x] = smx[0]; }
}

__global__ void k_minmax(const float* __restrict__ pmn, const float* __restrict__ pmx,
                         float* __restrict__ mm, int nb) {
    __shared__ float smn[512], smx[512];
    int tid = threadIdx.x;
    float mn = 1e30f, mx = -1e30f;
    for (int i = tid; i < nb; i += 512) {
        mn = fminf(mn, pmn[i]);
        mx = fmaxf(mx, pmx[i]);
    }
    smn[tid] = mn; smx[tid] = mx;
    __syncthreads();
    for (int s = 256; s > 0; s >>= 1) {
        if (tid < s) {
            smn[tid] = fminf(smn[tid], smn[tid + s]);
            smx[tid] = fmaxf(smx[tid], smx[tid + s]);
        }
        __syncthreads();
    }
    if (tid == 0) { mm[0] = smn[0]; mm[1] = smx[0]; }
}

__global__ void k_nrm(const float* __restrict__ y, const float* __restrict__ mm,
                      float* __restrict__ out, int n) {
    int i = blockIdx.x * 256 + threadIdx.x;
    if (i >= n) return;
    float mn = mm[0], mx = mm[1];
    out[i] = (y[i] - mn) / (mx - mn);
}

// ================= launch =================
extern "C" void kernel_launch(void* const* d_in, const int* in_sizes, int n_in,
                              void* d_out, int out_size, void* d_ws, size_t ws_size,
                              hipStream_t stream) {
    const float* x   = (const float*)d_in[0];
    const int*   ei  = (const int*)d_in[1];
    const float* ep  = (const float*)d_in[2];
    const float* W1  = (const float*)d_in[3];
    const float* b1  = (const float*)d_in[4];
    const float* W2  = (const float*)d_in[5];
    const float* b2  = (const float*)d_in[6];
    const float* W3  = (const float*)d_in[7];
    const float* b3  = (const float*)d_in[8];
    const float* Wm1 = (const float*)d_in[9];
    const float* bm1 = (const float*)d_in[10];
    const float* Wm2 = (const float*)d_in[11];
    const float* bm2 = (const float*)d_in[12];

    const int n = in_sizes[0] / NF;   // 100000
    const int E = in_sizes[2];        // 1600000
    const int* srcv = ei;
    const int* dstv = ei + E;
    const int tot = E + n;

    float* ws = (float*)d_ws;
    size_t pos = 0;
    auto alloc = [&](size_t cnt) {
        float* p = ws + pos;
        pos += (cnt + 255) & ~(size_t)255;
        return p;
    };
    float*  dinv = alloc(n);
    int*    cnt  = (int*)alloc(n);
    int*    rs   = (int*)alloc(n + 1);
    int*    rank = (int*)alloc(E);
    int*    btot = (int*)alloc(1024);
    int2*   csr  = (int2*)alloc((size_t)tot * 2);
    float*  y    = alloc(n);
    float*  pmn  = alloc(1024);
    float*  pmx  = alloc(1024);
    float*  mm   = alloc(2);
    float*  bufA = alloc((size_t)n * NF);              // fp32 agg
    ushort* bufH = (ushort*)alloc((size_t)n * NF / 2); // bf16 H

    const int TPB = 256;
    int gn  = (n + TPB - 1) / TPB;
    int gE  = (E + TPB - 1) / TPB;
    int gT  = (tot + TPB - 1) / TPB;
    int gG  = (n + 15) / 16;
    int gW  = (n * 64 + TPB - 1) / TPB;     // gather: 4 nodes/block
    int gH  = (n + TPB - 1) / TPB;
    int nb  = (n + 1023) / 1024;            // scan blocks

    // ---- CSR build (single atomic pass; reused by all 3 layers) ----
    k_initcnt<<<gn, TPB, 0, stream>>>(cnt, n);
    k_rank<<<gE, TPB, 0, stream>>>(dstv, cnt, rank, E);
    k_scan1<<<nb, TPB, 0, stream>>>(cnt, rs, btot, n);
    k_scan2<<<1, 64, 0, stream>>>(btot, nb);
    k_scan3<<<nb, TPB, 0, stream>>>(rs, btot, n, tot);
    k_fill<<<gT, TPB, 0, stream>>>(srcv, dstv, ep, rs, rank, csr, E, n);
    k_deg<<<gn, TPB, 0, stream>>>(csr, rs, dinv, n);
    k_wnorm<<<gn, TPB, 0, stream>>>(csr, rs, dinv, n);

    // ---- layer 1 ----
    k_gemm<0><<<gG, TPB, 0, stream>>>(x, W1, bufH, n);
    k_gather<<<gW, TPB, 0, stream>>>(csr, rs, bufH, b1, bufA, n);
    // ---- layer 2 ----
    k_gemm<1><<<gG, TPB, 0, stream>>>(bufA, W2, bufH, n);
    k_gather<<<gW, TPB, 0, stream>>>(csr, rs, bufH, b2, bufA, n);
    // ---- layer 3 ----
    k_gemm<1><<<gG, TPB, 0, stream>>>(bufA, W3, bufH, n);
    k_gather<<<gW, TPB, 0, stream>>>(csr, rs, bufH, b3, bufA, n);

    // ---- head + minmax + normalize ----
    k_head<<<gH, TPB, 0, stream>>>(bufA, Wm1, bm1, Wm2, bm2, y, pmn, pmx, n);
    k_minmax<<<1, 512, 0, stream>>>(pmn, pmx, mm, gH);
    k_nrm<<<gn, TPB, 0, stream>>>(y, mm, (float*)d_out, n);
}